// Round 1
// baseline (585.091 us; speedup 1.0000x reference)
//
#include <hip/hip_runtime.h>
#include <hip/hip_bf16.h>

#define H   2048
#define E   16
#define TK  4
#define I2  1536
#define IN  768

typedef __attribute__((ext_vector_type(8))) short bf16x8;
typedef __attribute__((ext_vector_type(4))) float f32x4;

__device__ __forceinline__ short f2bf(float f) {
  union { float f; unsigned u; } v; v.f = f;
  unsigned r = (v.u + 0x7FFFu + ((v.u >> 16) & 1u)) >> 16;
  return (short)r;
}

// ---------------- router: logits -> top4 -> normalized weights -------------
__global__ __launch_bounds__(256) void router_kernel(
    const float* __restrict__ x, const float* __restrict__ rw,
    int* __restrict__ cnt, int* __restrict__ tke, float* __restrict__ tkw) {
  const int t = blockIdx.x;
  const int lane = threadIdx.x & 63;
  const int wave = threadIdx.x >> 6;
  __shared__ float logits[E];
  const float* xr = x + (size_t)t * H;
  for (int ee = 0; ee < 4; ++ee) {
    const int e = wave * 4 + ee;
    const float* w = rw + (size_t)e * H;
    float s = 0.f;
    for (int k = lane; k < H; k += 64) s += xr[k] * w[k];
    for (int off = 32; off > 0; off >>= 1) s += __shfl_down(s, off);
    if (lane == 0) logits[e] = s;
  }
  __syncthreads();
  if (threadIdx.x == 0) {
    float l[E];
    for (int e = 0; e < E; ++e) l[e] = logits[e];
    int idx[TK]; float v[TK];
    for (int k = 0; k < TK; ++k) {
      int bi = 0; float bv = -3.4e38f;
      for (int e = 0; e < E; ++e) if (l[e] > bv) { bv = l[e]; bi = e; }
      idx[k] = bi; v[k] = bv; l[bi] = -3.4e38f;
    }
    // normalized top-k of softmax == softmax over the top-k logits
    const float m = v[0];
    float p[TK]; float z = 0.f;
    for (int k = 0; k < TK; ++k) { p[k] = expf(v[k] - m); z += p[k]; }
    const float rz = 1.f / z;
    for (int k = 0; k < TK; ++k) {
      tke[t * TK + k] = idx[k];
      tkw[t * TK + k] = p[k] * rz;
      atomicAdd(&cnt[idx[k]], 1);
    }
  }
}

// ---------------- 16-element exclusive scan --------------------------------
__global__ void scan_kernel(const int* __restrict__ cnt, int* __restrict__ offs) {
  if (threadIdx.x == 0) {
    int s = 0;
    for (int e = 0; e < E; ++e) { offs[e] = s; s += cnt[e]; }
    offs[E] = s;
  }
}

// ---------------- scatter pairs into compact per-expert lists --------------
__global__ __launch_bounds__(256) void scatter_kernel(
    const int* __restrict__ tke, const float* __restrict__ tkw,
    const int* __restrict__ offs, int* __restrict__ cursor,
    int* __restrict__ tok, float* __restrict__ pw) {
  const int i = blockIdx.x * 256 + threadIdx.x;
  const int e = tke[i];
  const int pos = atomicAdd(&cursor[e], 1);
  const int dst = offs[e] + pos;
  tok[dst] = i >> 2;
  pw[dst] = tkw[i];
}

// ---------------- gate_up GEMM + silu*up*w epilogue -> h (bf16) ------------
// grid: (IN/64, T/64, E). block 256 = 4 waves (2x2), each wave 32x32 of gate
// and 32x32 of up. K = 2048, BK = 32.
__global__ __launch_bounds__(256) void gateup_kernel(
    const float* __restrict__ x, const float* __restrict__ gup,
    const int* __restrict__ offs, const int* __restrict__ tok,
    const float* __restrict__ pw, ushort* __restrict__ h, int P) {
  const int e = blockIdx.z;
  const int base = offs[e];
  const int Ce = offs[e + 1] - base;
  const int m0 = blockIdx.y * 64;
  if (m0 >= Ce) return;
  const int n0 = blockIdx.x * 64;
  __shared__ short As[64][40];
  __shared__ short Bg[64][40];
  __shared__ short Bu[64][40];
  const int tid = threadIdx.x;
  // A staging role: one 16B octet per thread
  const int rowA = tid >> 2, octA = tid & 3;
  int ti = base + m0 + rowA; if (ti > P - 1) ti = P - 1;
  const int tA = tok[ti];
  const float* aptr = x + (size_t)tA * H + octA * 8;
  // B staging role: column cB, k-octet octB
  const int cB = tid & 63, octB = tid >> 6;
  const float* bg = gup + (size_t)e * H * I2 + (size_t)(octB * 8) * I2 + n0 + cB;
  const float* bu = bg + IN;
  const int lane = tid & 63, wave = tid >> 6;
  const int wm = wave >> 1, wn = wave & 1;
  f32x4 accg[2][2];
  f32x4 accu[2][2];
#pragma unroll
  for (int a = 0; a < 2; ++a)
#pragma unroll
    for (int b = 0; b < 2; ++b) {
      accg[a][b] = (f32x4){0.f, 0.f, 0.f, 0.f};
      accu[a][b] = (f32x4){0.f, 0.f, 0.f, 0.f};
    }

  for (int k0 = 0; k0 < H; k0 += 32) {
    const float4 a0 = *(const float4*)(aptr);
    const float4 a1 = *(const float4*)(aptr + 4);
    float gv[8], uv[8];
#pragma unroll
    for (int i = 0; i < 8; ++i) { gv[i] = bg[(size_t)i * I2]; uv[i] = bu[(size_t)i * I2]; }
    __syncthreads();
    bf16x8 ap;
    ap[0] = f2bf(a0.x); ap[1] = f2bf(a0.y); ap[2] = f2bf(a0.z); ap[3] = f2bf(a0.w);
    ap[4] = f2bf(a1.x); ap[5] = f2bf(a1.y); ap[6] = f2bf(a1.z); ap[7] = f2bf(a1.w);
    *(bf16x8*)&As[rowA][octA * 8] = ap;
    bf16x8 gp, up8;
#pragma unroll
    for (int i = 0; i < 8; ++i) { gp[i] = f2bf(gv[i]); up8[i] = f2bf(uv[i]); }
    *(bf16x8*)&Bg[cB][octB * 8] = gp;
    *(bf16x8*)&Bu[cB][octB * 8] = up8;
    __syncthreads();
    aptr += 32; bg += (size_t)32 * I2; bu += (size_t)32 * I2;

    bf16x8 af[2], gf[2], uf[2];
#pragma unroll
    for (int fm = 0; fm < 2; ++fm)
      af[fm] = *(bf16x8*)&As[wm * 32 + fm * 16 + (lane & 15)][(lane >> 4) * 8];
#pragma unroll
    for (int fn = 0; fn < 2; ++fn) {
      gf[fn] = *(bf16x8*)&Bg[wn * 32 + fn * 16 + (lane & 15)][(lane >> 4) * 8];
      uf[fn] = *(bf16x8*)&Bu[wn * 32 + fn * 16 + (lane & 15)][(lane >> 4) * 8];
    }
#pragma unroll
    for (int fm = 0; fm < 2; ++fm)
#pragma unroll
      for (int fn = 0; fn < 2; ++fn) {
        accg[fm][fn] = __builtin_amdgcn_mfma_f32_16x16x32_bf16(af[fm], gf[fn], accg[fm][fn], 0, 0, 0);
        accu[fm][fn] = __builtin_amdgcn_mfma_f32_16x16x32_bf16(af[fm], uf[fn], accu[fm][fn], 0, 0, 0);
      }
  }

  // epilogue: h = silu(g) * u * w  (bf16)
#pragma unroll
  for (int fm = 0; fm < 2; ++fm) {
    const int rbase = wm * 32 + fm * 16 + ((lane >> 4) << 2);
#pragma unroll
    for (int j = 0; j < 4; ++j) {
      const int row = m0 + rbase + j;
      if (row < Ce) {
        const float wgt = pw[base + row];
#pragma unroll
        for (int fn = 0; fn < 2; ++fn) {
          const float g = accg[fm][fn][j];
          const float u = accu[fm][fn][j];
          const float hv = (g / (1.f + expf(-g))) * u * wgt;
          const int col = n0 + wn * 32 + fn * 16 + (lane & 15);
          h[(size_t)(base + row) * IN + col] = (ushort)f2bf(hv);
        }
      }
    }
  }
}

// ---------------- down GEMM, atomicAdd into out ----------------------------
// grid: (H/64, T/64, E). K = 768, BK = 32.
__global__ __launch_bounds__(256) void down_kernel(
    const ushort* __restrict__ h, const float* __restrict__ dwn,
    const int* __restrict__ offs, const int* __restrict__ tok,
    float* __restrict__ out, int P) {
  const int e = blockIdx.z;
  const int base = offs[e];
  const int Ce = offs[e + 1] - base;
  const int m0 = blockIdx.y * 64;
  if (m0 >= Ce) return;
  const int n0 = blockIdx.x * 64;
  __shared__ short As[64][40];
  __shared__ short Bs[64][40];
  const int tid = threadIdx.x;
  const int rowA = tid >> 2, octA = tid & 3;
  const bool avalid = (m0 + rowA) < Ce;
  const ushort* aptr = h + (size_t)(base + m0 + rowA) * IN + octA * 8;
  const int cB = tid & 63, octB = tid >> 6;
  const float* bp = dwn + (size_t)e * IN * H + (size_t)(octB * 8) * H + n0 + cB;
  const int lane = tid & 63, wave = tid >> 6;
  const int wm = wave >> 1, wn = wave & 1;
  f32x4 acc[2][2];
#pragma unroll
  for (int a = 0; a < 2; ++a)
#pragma unroll
    for (int b = 0; b < 2; ++b) acc[a][b] = (f32x4){0.f, 0.f, 0.f, 0.f};

  for (int k0 = 0; k0 < IN; k0 += 32) {
    bf16x8 av = (bf16x8){0, 0, 0, 0, 0, 0, 0, 0};
    if (avalid) av = *(const bf16x8*)(aptr);
    float bv[8];
#pragma unroll
    for (int i = 0; i < 8; ++i) bv[i] = bp[(size_t)i * H];
    __syncthreads();
    *(bf16x8*)&As[rowA][octA * 8] = av;
    bf16x8 bpk;
#pragma unroll
    for (int i = 0; i < 8; ++i) bpk[i] = f2bf(bv[i]);
    *(bf16x8*)&Bs[cB][octB * 8] = bpk;
    __syncthreads();
    aptr += 32; bp += (size_t)32 * H;

    bf16x8 af[2], bf[2];
#pragma unroll
    for (int fm = 0; fm < 2; ++fm)
      af[fm] = *(bf16x8*)&As[wm * 32 + fm * 16 + (lane & 15)][(lane >> 4) * 8];
#pragma unroll
    for (int fn = 0; fn < 2; ++fn)
      bf[fn] = *(bf16x8*)&Bs[wn * 32 + fn * 16 + (lane & 15)][(lane >> 4) * 8];
#pragma unroll
    for (int fm = 0; fm < 2; ++fm)
#pragma unroll
      for (int fn = 0; fn < 2; ++fn)
        acc[fm][fn] = __builtin_amdgcn_mfma_f32_16x16x32_bf16(af[fm], bf[fn], acc[fm][fn], 0, 0, 0);
  }

#pragma unroll
  for (int fm = 0; fm < 2; ++fm) {
    const int rbase = wm * 32 + fm * 16 + ((lane >> 4) << 2);
#pragma unroll
    for (int j = 0; j < 4; ++j) {
      const int row = m0 + rbase + j;
      if (row < Ce) {
        const int t = tok[base + row];
#pragma unroll
        for (int fn = 0; fn < 2; ++fn) {
          const int col = n0 + wn * 32 + fn * 16 + (lane & 15);
          atomicAdd(&out[(size_t)t * H + col], acc[fm][fn][j]);
        }
      }
    }
  }
}

extern "C" void kernel_launch(void* const* d_in, const int* in_sizes, int n_in,
                              void* d_out, int out_size, void* d_ws, size_t ws_size,
                              hipStream_t stream) {
  const float* x   = (const float*)d_in[0];
  const float* rw  = (const float*)d_in[1];
  const float* gup = (const float*)d_in[2];
  const float* dwn = (const float*)d_in[3];
  float* out = (float*)d_out;
  const int T = in_sizes[0] / H;  // 1024
  const int P = T * TK;           // 4096

  char* ws = (char*)d_ws;
  int*    cnt    = (int*)(ws + 0);      // 16
  int*    cursor = (int*)(ws + 64);     // 16
  int*    offs   = (int*)(ws + 128);    // 17
  int*    tke    = (int*)(ws + 256);            // P ints
  float*  tkw    = (float*)(ws + 256 + 4 * (size_t)P);
  int*    tok    = (int*)(ws + 256 + 8 * (size_t)P);
  float*  pw     = (float*)(ws + 256 + 12 * (size_t)P);
  ushort* hbuf   = (ushort*)(ws + 256 + 16 * (size_t)P); // P*IN bf16

  hipMemsetAsync(ws, 0, 256, stream);
  hipMemsetAsync(d_out, 0, (size_t)out_size * sizeof(float), stream);

  router_kernel<<<T, 256, 0, stream>>>(x, rw, cnt, tke, tkw);
  scan_kernel<<<1, 64, 0, stream>>>(cnt, offs);
  scatter_kernel<<<P / 256, 256, 0, stream>>>(tke, tkw, offs, cursor, tok, pw);
  gateup_kernel<<<dim3(IN / 64, T / 64, E), 256, 0, stream>>>(x, gup, offs, tok, pw, hbuf, P);
  down_kernel<<<dim3(H / 64, T / 64, E), 256, 0, stream>>>(hbuf, dwn, offs, tok, out, P);
}

// Round 4
// 579.674 us; speedup vs baseline: 1.0093x; 1.0093x over previous
//
#include <hip/hip_runtime.h>
#include <hip/hip_bf16.h>

#define H   2048
#define E   16
#define TK  4
#define I2  1536
#define IN  768

typedef __attribute__((ext_vector_type(8))) short bf16x8;
typedef __attribute__((ext_vector_type(4))) float f32x4;

__device__ __forceinline__ short f2bf(float f) {
  union { float f; unsigned u; } v; v.f = f;
  unsigned r = (v.u + 0x7FFFu + ((v.u >> 16) & 1u)) >> 16;
  return (short)r;
}

__device__ __forceinline__ void gload16(const ushort* g, ushort* l) {
  __builtin_amdgcn_global_load_lds(
      (const __attribute__((address_space(1))) void*)g,
      (__attribute__((address_space(3))) void*)l, 16, 0, 0);
}

// ---------------- router: logits -> top4 -> normalized weights -------------
__global__ __launch_bounds__(256) void router_kernel(
    const float* __restrict__ x, const float* __restrict__ rw,
    int* __restrict__ cnt, int* __restrict__ tke, float* __restrict__ tkw) {
  const int t = blockIdx.x;
  const int lane = threadIdx.x & 63;
  const int wave = threadIdx.x >> 6;
  __shared__ float logits[E];
  const float* xr = x + (size_t)t * H;
  for (int ee = 0; ee < 4; ++ee) {
    const int e = wave * 4 + ee;
    const float* w = rw + (size_t)e * H;
    float s = 0.f;
    for (int k = lane; k < H; k += 64) s += xr[k] * w[k];
    for (int off = 32; off > 0; off >>= 1) s += __shfl_down(s, off);
    if (lane == 0) logits[e] = s;
  }
  __syncthreads();
  if (threadIdx.x == 0) {
    float l[E];
    for (int e = 0; e < E; ++e) l[e] = logits[e];
    int idx[TK]; float v[TK];
    for (int k = 0; k < TK; ++k) {
      int bi = 0; float bv = -3.4e38f;
      for (int e = 0; e < E; ++e) if (l[e] > bv) { bv = l[e]; bi = e; }
      idx[k] = bi; v[k] = bv; l[bi] = -3.4e38f;
    }
    const float m = v[0];
    float p[TK]; float z = 0.f;
    for (int k = 0; k < TK; ++k) { p[k] = expf(v[k] - m); z += p[k]; }
    const float rz = 1.f / z;
    for (int k = 0; k < TK; ++k) {
      tke[t * TK + k] = idx[k];
      tkw[t * TK + k] = p[k] * rz;
      atomicAdd(&cnt[idx[k]], 1);
    }
  }
}

__global__ void scan_kernel(const int* __restrict__ cnt, int* __restrict__ offs) {
  if (threadIdx.x == 0) {
    int s = 0;
    for (int e = 0; e < E; ++e) { offs[e] = s; s += cnt[e]; }
    offs[E] = s;
  }
}

__global__ __launch_bounds__(256) void scatter_kernel(
    const int* __restrict__ tke, const float* __restrict__ tkw,
    const int* __restrict__ offs, int* __restrict__ cursor,
    int* __restrict__ tok, float* __restrict__ pw) {
  const int i = blockIdx.x * 256 + threadIdx.x;
  const int e = tke[i];
  const int pos = atomicAdd(&cursor[e], 1);
  const int dst = offs[e] + pos;
  tok[dst] = i >> 2;
  pw[dst] = tkw[i];
}

// ---------------- prep: transpose + cvt fp32 [R][C] -> bf16 [C][R] ---------
__global__ __launch_bounds__(256) void tcvt_kernel(
    const float* __restrict__ in, ushort* __restrict__ out, int R, int C) {
  const size_t eb = (size_t)blockIdx.z * R * C;
  const int r0 = blockIdx.y * 64, c0 = blockIdx.x * 64;
  __shared__ ushort t[64][68];
  const int tid = threadIdx.x;
  const int rr = tid >> 4;
  const int cc4 = (tid & 15) * 4;
#pragma unroll
  for (int i = 0; i < 4; ++i) {
    const int r = i * 16 + rr;
    float4 v = *(const float4*)(in + eb + (size_t)(r0 + r) * C + c0 + cc4);
    t[cc4 + 0][r] = (ushort)f2bf(v.x); t[cc4 + 1][r] = (ushort)f2bf(v.y);
    t[cc4 + 2][r] = (ushort)f2bf(v.z); t[cc4 + 3][r] = (ushort)f2bf(v.w);
  }
  __syncthreads();
  const int cr = tid >> 4;
  const int rr4 = (tid & 15) * 4;
#pragma unroll
  for (int i = 0; i < 4; ++i) {
    const int c = i * 16 + cr;
    ushort4 o;
    o.x = t[c][rr4]; o.y = t[c][rr4 + 1]; o.z = t[c][rr4 + 2]; o.w = t[c][rr4 + 3];
    *(ushort4*)(out + eb + (size_t)(c0 + c) * R + r0 + rr4) = o;
  }
}

__global__ __launch_bounds__(256) void xcvt_kernel(
    const float* __restrict__ x, ushort* __restrict__ xb, int n4) {
  const int i = blockIdx.x * 256 + threadIdx.x;
  if (i < n4) {
    float4 v = ((const float4*)x)[i];
    ushort4 o;
    o.x = (ushort)f2bf(v.x); o.y = (ushort)f2bf(v.y);
    o.z = (ushort)f2bf(v.z); o.w = (ushort)f2bf(v.w);
    ((ushort4*)xb)[i] = o;
  }
}

// ---------------- gateup2: bf16 GEMM, gload_lds + swizzled LDS -------------
// grid (IN/64, T/64, E), 256 thr = 4 waves (2m x 2n), tile 64M x 64N(g)+64N(u),
// BK=64. LDS tiles [64 rows][64 k] bf16 linear; slot-swizzle s = q ^ (row&7).
__global__ __launch_bounds__(256) void gateup2_kernel(
    const ushort* __restrict__ xb, const ushort* __restrict__ gupT,
    const int* __restrict__ offs, const int* __restrict__ tok,
    const float* __restrict__ pw, ushort* __restrict__ h, int P) {
  const int e = blockIdx.z;
  const int base = offs[e];
  const int Ce = offs[e + 1] - base;
  const int m0 = blockIdx.y * 64;
  if (m0 >= Ce) return;
  const int n0 = blockIdx.x * 64;
  __shared__ ushort As[64 * 64];
  __shared__ ushort Bg[64 * 64];
  __shared__ ushort Bu[64 * 64];
  const int tid = threadIdx.x;
  const int lane = tid & 63, wave = tid >> 6;
  const int wm = wave >> 1, wn = wave & 1;

  // staging: wave stages rows [wave*16, wave*16+16), 2 gloads of 8 rows each.
  const int srow = lane >> 3;           // 0..7, == row&7 for both gloads
  const int schunk = ((lane & 7) ^ srow) << 3;  // swizzled k-chunk (elements)
  int ar0 = base + m0 + wave * 16 + srow;
  int ar1 = ar0 + 8;
  if (ar0 >= P) ar0 = P - 1;
  if (ar1 >= P) ar1 = P - 1;
  const ushort* aS0 = xb + (size_t)tok[ar0] * H + schunk;
  const ushort* aS1 = xb + (size_t)tok[ar1] * H + schunk;
  const int bc0 = wave * 16 + srow, bc1 = bc0 + 8;
  const size_t gB = (size_t)e * I2 * H;
  const ushort* gS0 = gupT + gB + (size_t)(n0 + bc0) * H + schunk;
  const ushort* gS1 = gupT + gB + (size_t)(n0 + bc1) * H + schunk;
  const ushort* uS0 = gupT + gB + (size_t)(IN + n0 + bc0) * H + schunk;
  const ushort* uS1 = gupT + gB + (size_t)(IN + n0 + bc1) * H + schunk;
  ushort* aD0 = As + (wave * 16 + 0) * 64;
  ushort* aD1 = As + (wave * 16 + 8) * 64;
  ushort* gD0 = Bg + (wave * 16 + 0) * 64;
  ushort* gD1 = Bg + (wave * 16 + 8) * 64;
  ushort* uD0 = Bu + (wave * 16 + 0) * 64;
  ushort* uD1 = Bu + (wave * 16 + 8) * 64;

  // fragment read offsets (elements), swizzle-matched
  const int la = lane & 15, q = lane >> 4;
  int aoff[2][2], boff[2][2];
#pragma unroll
  for (int s = 0; s < 2; ++s) {
    const int qq = s * 4 + q;
#pragma unroll
    for (int f = 0; f < 2; ++f) {
      const int Ra = wm * 32 + f * 16 + la;
      aoff[s][f] = Ra * 64 + ((qq ^ (Ra & 7)) << 3);
      const int Rb = wn * 32 + f * 16 + la;
      boff[s][f] = Rb * 64 + ((qq ^ (Rb & 7)) << 3);
    }
  }

  f32x4 accg[2][2], accu[2][2];
#pragma unroll
  for (int a = 0; a < 2; ++a)
#pragma unroll
    for (int b = 0; b < 2; ++b) {
      accg[a][b] = (f32x4){0.f, 0.f, 0.f, 0.f};
      accu[a][b] = (f32x4){0.f, 0.f, 0.f, 0.f};
    }

  for (int k0 = 0; k0 < H; k0 += 64) {
    gload16(aS0, aD0); gload16(aS1, aD1);
    gload16(gS0, gD0); gload16(gS1, gD1);
    gload16(uS0, uD0); gload16(uS1, uD1);
    aS0 += 64; aS1 += 64; gS0 += 64; gS1 += 64; uS0 += 64; uS1 += 64;
    __syncthreads();
#pragma unroll
    for (int s = 0; s < 2; ++s) {
      bf16x8 af[2], gf[2], uf[2];
#pragma unroll
      for (int f = 0; f < 2; ++f) {
        af[f] = *(const bf16x8*)&As[aoff[s][f]];
        gf[f] = *(const bf16x8*)&Bg[boff[s][f]];
        uf[f] = *(const bf16x8*)&Bu[boff[s][f]];
      }
#pragma unroll
      for (int fm = 0; fm < 2; ++fm)
#pragma unroll
        for (int fn = 0; fn < 2; ++fn) {
          accg[fm][fn] = __builtin_amdgcn_mfma_f32_16x16x32_bf16(af[fm], gf[fn], accg[fm][fn], 0, 0, 0);
          accu[fm][fn] = __builtin_amdgcn_mfma_f32_16x16x32_bf16(af[fm], uf[fn], accu[fm][fn], 0, 0, 0);
        }
    }
    __syncthreads();
  }

#pragma unroll
  for (int fm = 0; fm < 2; ++fm) {
    const int rbase = wm * 32 + fm * 16 + ((lane >> 4) << 2);
#pragma unroll
    for (int j = 0; j < 4; ++j) {
      const int row = m0 + rbase + j;
      if (row < Ce) {
        const float wgt = pw[base + row];
#pragma unroll
        for (int fn = 0; fn < 2; ++fn) {
          const float g = accg[fm][fn][j];
          const float u = accu[fm][fn][j];
          const float hv = (g / (1.f + expf(-g))) * u * wgt;
          const int col = n0 + wn * 32 + fn * 16 + (lane & 15);
          h[(size_t)(base + row) * IN + col] = (ushort)f2bf(hv);
        }
      }
    }
  }
}

// ---------------- down2: bf16 GEMM, atomicAdd epilogue ---------------------
// grid (H/64, T/64, E), BK=64, K=IN=768.
__global__ __launch_bounds__(256) void down2_kernel(
    const ushort* __restrict__ h, const ushort* __restrict__ dT,
    const int* __restrict__ offs, const int* __restrict__ tok,
    float* __restrict__ out, int P) {
  const int e = blockIdx.z;
  const int base = offs[e];
  const int Ce = offs[e + 1] - base;
  const int m0 = blockIdx.y * 64;
  if (m0 >= Ce) return;
  const int n0 = blockIdx.x * 64;
  __shared__ ushort As[64 * 64];
  __shared__ ushort Bs[64 * 64];
  const int tid = threadIdx.x;
  const int lane = tid & 63, wave = tid >> 6;
  const int wm = wave >> 1, wn = wave & 1;

  const int srow = lane >> 3;
  const int schunk = ((lane & 7) ^ srow) << 3;
  int ar0 = base + m0 + wave * 16 + srow;
  int ar1 = ar0 + 8;
  if (ar0 >= P) ar0 = P - 1;
  if (ar1 >= P) ar1 = P - 1;
  const ushort* aS0 = h + (size_t)ar0 * IN + schunk;
  const ushort* aS1 = h + (size_t)ar1 * IN + schunk;
  const int bc0 = wave * 16 + srow, bc1 = bc0 + 8;
  const ushort* bS0 = dT + ((size_t)e * H + n0 + bc0) * IN + schunk;
  const ushort* bS1 = dT + ((size_t)e * H + n0 + bc1) * IN + schunk;
  ushort* aD0 = As + (wave * 16 + 0) * 64;
  ushort* aD1 = As + (wave * 16 + 8) * 64;
  ushort* bD0 = Bs + (wave * 16 + 0) * 64;
  ushort* bD1 = Bs + (wave * 16 + 8) * 64;

  const int la = lane & 15, q = lane >> 4;
  int aoff[2][2], boff[2][2];
#pragma unroll
  for (int s = 0; s < 2; ++s) {
    const int qq = s * 4 + q;
#pragma unroll
    for (int f = 0; f < 2; ++f) {
      const int Ra = wm * 32 + f * 16 + la;
      aoff[s][f] = Ra * 64 + ((qq ^ (Ra & 7)) << 3);
      const int Rb = wn * 32 + f * 16 + la;
      boff[s][f] = Rb * 64 + ((qq ^ (Rb & 7)) << 3);
    }
  }

  f32x4 acc[2][2];
#pragma unroll
  for (int a = 0; a < 2; ++a)
#pragma unroll
    for (int b = 0; b < 2; ++b) acc[a][b] = (f32x4){0.f, 0.f, 0.f, 0.f};

  for (int k0 = 0; k0 < IN; k0 += 64) {
    gload16(aS0, aD0); gload16(aS1, aD1);
    gload16(bS0, bD0); gload16(bS1, bD1);
    aS0 += 64; aS1 += 64; bS0 += 64; bS1 += 64;
    __syncthreads();
#pragma unroll
    for (int s = 0; s < 2; ++s) {
      bf16x8 af[2], bf[2];
#pragma unroll
      for (int f = 0; f < 2; ++f) {
        af[f] = *(const bf16x8*)&As[aoff[s][f]];
        bf[f] = *(const bf16x8*)&Bs[boff[s][f]];
      }
#pragma unroll
      for (int fm = 0; fm < 2; ++fm)
#pragma unroll
        for (int fn = 0; fn < 2; ++fn)
          acc[fm][fn] = __builtin_amdgcn_mfma_f32_16x16x32_bf16(af[fm], bf[fn], acc[fm][fn], 0, 0, 0);
    }
    __syncthreads();
  }

#pragma unroll
  for (int fm = 0; fm < 2; ++fm) {
    const int rbase = wm * 32 + fm * 16 + ((lane >> 4) << 2);
#pragma unroll
    for (int j = 0; j < 4; ++j) {
      const int row = m0 + rbase + j;
      if (row < Ce) {
        const int t = tok[base + row];
#pragma unroll
        for (int fn = 0; fn < 2; ++fn) {
          const int col = n0 + wn * 32 + fn * 16 + (lane & 15);
          atomicAdd(&out[(size_t)t * H + col], acc[fm][fn][j]);
        }
      }
    }
  }
}

// ======================= legacy fallback (round-1, fp32 staging) ===========
__global__ __launch_bounds__(256) void gateup1_kernel(
    const float* __restrict__ x, const float* __restrict__ gup,
    const int* __restrict__ offs, const int* __restrict__ tok,
    const float* __restrict__ pw, ushort* __restrict__ h, int P) {
  const int e = blockIdx.z;
  const int base = offs[e];
  const int Ce = offs[e + 1] - base;
  const int m0 = blockIdx.y * 64;
  if (m0 >= Ce) return;
  const int n0 = blockIdx.x * 64;
  __shared__ short As[64][40];
  __shared__ short BgL[64][40];
  __shared__ short BuL[64][40];
  const int tid = threadIdx.x;
  const int rowA = tid >> 2, octA = tid & 3;
  int ti = base + m0 + rowA; if (ti > P - 1) ti = P - 1;
  const int tA = tok[ti];
  const float* aptr = x + (size_t)tA * H + octA * 8;
  const int cB = tid & 63, octB = tid >> 6;
  const float* bg = gup + (size_t)e * H * I2 + (size_t)(octB * 8) * I2 + n0 + cB;
  const float* bu = bg + IN;
  const int lane = tid & 63, wave = tid >> 6;
  const int wm = wave >> 1, wn = wave & 1;
  f32x4 accg[2][2], accu[2][2];
#pragma unroll
  for (int a = 0; a < 2; ++a)
#pragma unroll
    for (int b = 0; b < 2; ++b) {
      accg[a][b] = (f32x4){0.f, 0.f, 0.f, 0.f};
      accu[a][b] = (f32x4){0.f, 0.f, 0.f, 0.f};
    }
  for (int k0 = 0; k0 < H; k0 += 32) {
    const float4 a0 = *(const float4*)(aptr);
    const float4 a1 = *(const float4*)(aptr + 4);
    float gv[8], uv[8];
#pragma unroll
    for (int i = 0; i < 8; ++i) { gv[i] = bg[(size_t)i * I2]; uv[i] = bu[(size_t)i * I2]; }
    __syncthreads();
    bf16x8 ap;
    ap[0] = f2bf(a0.x); ap[1] = f2bf(a0.y); ap[2] = f2bf(a0.z); ap[3] = f2bf(a0.w);
    ap[4] = f2bf(a1.x); ap[5] = f2bf(a1.y); ap[6] = f2bf(a1.z); ap[7] = f2bf(a1.w);
    *(bf16x8*)&As[rowA][octA * 8] = ap;
    bf16x8 gp, up8;
#pragma unroll
    for (int i = 0; i < 8; ++i) { gp[i] = f2bf(gv[i]); up8[i] = f2bf(uv[i]); }
    *(bf16x8*)&BgL[cB][octB * 8] = gp;
    *(bf16x8*)&BuL[cB][octB * 8] = up8;
    __syncthreads();
    aptr += 32; bg += (size_t)32 * I2; bu += (size_t)32 * I2;
    bf16x8 af[2], gf[2], uf[2];
#pragma unroll
    for (int fm = 0; fm < 2; ++fm)
      af[fm] = *(bf16x8*)&As[wm * 32 + fm * 16 + (lane & 15)][(lane >> 4) * 8];
#pragma unroll
    for (int fn = 0; fn < 2; ++fn) {
      gf[fn] = *(bf16x8*)&BgL[wn * 32 + fn * 16 + (lane & 15)][(lane >> 4) * 8];
      uf[fn] = *(bf16x8*)&BuL[wn * 32 + fn * 16 + (lane & 15)][(lane >> 4) * 8];
    }
#pragma unroll
    for (int fm = 0; fm < 2; ++fm)
#pragma unroll
      for (int fn = 0; fn < 2; ++fn) {
        accg[fm][fn] = __builtin_amdgcn_mfma_f32_16x16x32_bf16(af[fm], gf[fn], accg[fm][fn], 0, 0, 0);
        accu[fm][fn] = __builtin_amdgcn_mfma_f32_16x16x32_bf16(af[fm], uf[fn], accu[fm][fn], 0, 0, 0);
      }
  }
#pragma unroll
  for (int fm = 0; fm < 2; ++fm) {
    const int rbase = wm * 32 + fm * 16 + ((lane >> 4) << 2);
#pragma unroll
    for (int j = 0; j < 4; ++j) {
      const int row = m0 + rbase + j;
      if (row < Ce) {
        const float wgt = pw[base + row];
#pragma unroll
        for (int fn = 0; fn < 2; ++fn) {
          const float g = accg[fm][fn][j];
          const float u = accu[fm][fn][j];
          const float hv = (g / (1.f + expf(-g))) * u * wgt;
          const int col = n0 + wn * 32 + fn * 16 + (lane & 15);
          h[(size_t)(base + row) * IN + col] = (ushort)f2bf(hv);
        }
      }
    }
  }
}

__global__ __launch_bounds__(256) void down1_kernel(
    const ushort* __restrict__ h, const float* __restrict__ dwn,
    const int* __restrict__ offs, const int* __restrict__ tok,
    float* __restrict__ out, int P) {
  const int e = blockIdx.z;
  const int base = offs[e];
  const int Ce = offs[e + 1] - base;
  const int m0 = blockIdx.y * 64;
  if (m0 >= Ce) return;
  const int n0 = blockIdx.x * 64;
  __shared__ short As[64][40];
  __shared__ short Bs[64][40];
  const int tid = threadIdx.x;
  const int rowA = tid >> 2, octA = tid & 3;
  const bool avalid = (m0 + rowA) < Ce;
  const ushort* aptr = h + (size_t)(base + m0 + rowA) * IN + octA * 8;
  const int cB = tid & 63, octB = tid >> 6;
  const float* bp = dwn + (size_t)e * IN * H + (size_t)(octB * 8) * H + n0 + cB;
  const int lane = tid & 63, wave = tid >> 6;
  const int wm = wave >> 1, wn = wave & 1;
  f32x4 acc[2][2];
#pragma unroll
  for (int a = 0; a < 2; ++a)
#pragma unroll
    for (int b = 0; b < 2; ++b) acc[a][b] = (f32x4){0.f, 0.f, 0.f, 0.f};
  for (int k0 = 0; k0 < IN; k0 += 32) {
    bf16x8 av = (bf16x8){0, 0, 0, 0, 0, 0, 0, 0};
    if (avalid) av = *(const bf16x8*)(aptr);
    float bv[8];
#pragma unroll
    for (int i = 0; i < 8; ++i) bv[i] = bp[(size_t)i * H];
    __syncthreads();
    *(bf16x8*)&As[rowA][octA * 8] = av;
    bf16x8 bpk;
#pragma unroll
    for (int i = 0; i < 8; ++i) bpk[i] = f2bf(bv[i]);
    *(bf16x8*)&Bs[cB][octB * 8] = bpk;
    __syncthreads();
    aptr += 32; bp += (size_t)32 * H;
    bf16x8 af[2], bf[2];
#pragma unroll
    for (int fm = 0; fm < 2; ++fm)
      af[fm] = *(bf16x8*)&As[wm * 32 + fm * 16 + (lane & 15)][(lane >> 4) * 8];
#pragma unroll
    for (int fn = 0; fn < 2; ++fn)
      bf[fn] = *(bf16x8*)&Bs[wn * 32 + fn * 16 + (lane & 15)][(lane >> 4) * 8];
#pragma unroll
    for (int fm = 0; fm < 2; ++fm)
#pragma unroll
      for (int fn = 0; fn < 2; ++fn)
        acc[fm][fn] = __builtin_amdgcn_mfma_f32_16x16x32_bf16(af[fm], bf[fn], acc[fm][fn], 0, 0, 0);
  }
#pragma unroll
  for (int fm = 0; fm < 2; ++fm) {
    const int rbase = wm * 32 + fm * 16 + ((lane >> 4) << 2);
#pragma unroll
    for (int j = 0; j < 4; ++j) {
      const int row = m0 + rbase + j;
      if (row < Ce) {
        const int t = tok[base + row];
#pragma unroll
        for (int fn = 0; fn < 2; ++fn) {
          const int col = n0 + wn * 32 + fn * 16 + (lane & 15);
          atomicAdd(&out[(size_t)t * H + col], acc[fm][fn][j]);
        }
      }
    }
  }
}

extern "C" void kernel_launch(void* const* d_in, const int* in_sizes, int n_in,
                              void* d_out, int out_size, void* d_ws, size_t ws_size,
                              hipStream_t stream) {
  const float* x   = (const float*)d_in[0];
  const float* rw  = (const float*)d_in[1];
  const float* gup = (const float*)d_in[2];
  const float* dwn = (const float*)d_in[3];
  float* out = (float*)d_out;
  const int T = in_sizes[0] / H;  // 1024
  const int P = T * TK;           // 4096

  char* ws = (char*)d_ws;
  int*    cnt    = (int*)(ws + 0);
  int*    cursor = (int*)(ws + 64);
  int*    offs   = (int*)(ws + 128);
  int*    tke    = (int*)(ws + 256);
  float*  tkw    = (float*)(ws + 256 + 4 * (size_t)P);
  int*    tok    = (int*)(ws + 256 + 8 * (size_t)P);
  float*  pw     = (float*)(ws + 256 + 12 * (size_t)P);
  const size_t small_end = 256 + 16 * (size_t)P;  // 65792

  // full-path layout
  const size_t xbf_off  = small_end;                       // T*H*2     = 4 MB
  const size_t hbuf_off = xbf_off + (size_t)T * H * 2;     // P*IN*2    = 6.3 MB
  const size_t gupT_off = hbuf_off + (size_t)P * IN * 2;   // E*I2*H*2  = 100.7 MB
  const size_t dT_off   = gupT_off + (size_t)E * I2 * H * 2;
  const size_t need     = dT_off + (size_t)E * H * IN * 2; // ≈161.5 MB

  hipMemsetAsync(ws, 0, 256, stream);
  hipMemsetAsync(d_out, 0, (size_t)out_size * sizeof(float), stream);

  router_kernel<<<T, 256, 0, stream>>>(x, rw, cnt, tke, tkw);
  scan_kernel<<<1, 64, 0, stream>>>(cnt, offs);
  scatter_kernel<<<P / 256, 256, 0, stream>>>(tke, tkw, offs, cursor, tok, pw);

  if (ws_size >= need) {
    ushort* xbf  = (ushort*)(ws + xbf_off);
    ushort* hbuf = (ushort*)(ws + hbuf_off);
    ushort* gupT = (ushort*)(ws + gupT_off);
    ushort* dT   = (ushort*)(ws + dT_off);
    tcvt_kernel<<<dim3(I2 / 64, H / 64, E), 256, 0, stream>>>(gup, gupT, H, I2);
    tcvt_kernel<<<dim3(H / 64, IN / 64, E), 256, 0, stream>>>(dwn, dT, IN, H);
    xcvt_kernel<<<(T * H / 4 + 255) / 256, 256, 0, stream>>>(x, xbf, T * H / 4);
    gateup2_kernel<<<dim3(IN / 64, T / 64, E), 256, 0, stream>>>(xbf, gupT, offs, tok, pw, hbuf, P);
    down2_kernel<<<dim3(H / 64, T / 64, E), 256, 0, stream>>>(hbuf, dT, offs, tok, out, P);
  } else {
    ushort* hbuf = (ushort*)(ws + small_end);
    gateup1_kernel<<<dim3(IN / 64, T / 64, E), 256, 0, stream>>>(x, gup, offs, tok, pw, hbuf, P);
    down1_kernel<<<dim3(H / 64, T / 64, E), 256, 0, stream>>>(hbuf, dwn, offs, tok, out, P);
  }
}